// Round 1
// baseline (185.125 us; speedup 1.0000x reference)
//
#include <hip/hip_runtime.h>

#define NEG 0.2f
#define BN_EPS 1e-5f

__device__ __forceinline__ void fma4(float4& d, float a, const float4 b) {
  d.x = fmaf(a, b.x, d.x);
  d.y = fmaf(a, b.y, d.y);
  d.z = fmaf(a, b.z, d.z);
  d.w = fmaf(a, b.w, d.w);
}

__device__ __forceinline__ float4 leaky4(float4 v) {
  v.x = fmaxf(v.x, NEG * v.x);
  v.y = fmaxf(v.y, NEG * v.y);
  v.z = fmaxf(v.z, NEG * v.z);
  v.w = fmaxf(v.w, NEG * v.w);
  return v;
}

// One wave = 4 instances (16 lanes each); lane owns 4 output columns (float4).
// Block = 256 threads = 4 waves = 16 instances. Grid = 65536/16 = 4096 blocks.
__global__ __launch_bounds__(256, 2)
void enc_kernel(const float* __restrict__ adj, const float* __restrict__ noise,
                const float* __restrict__ W1p, const float* __restrict__ b1p,
                const float* __restrict__ W2p, const float* __restrict__ b2p,
                const float* __restrict__ Wmp, const float* __restrict__ bmp,
                const float* __restrict__ gmp, const float* __restrict__ betamp,
                const float* __restrict__ Wsp, const float* __restrict__ bsp,
                const float* __restrict__ gsp, const float* __restrict__ betasp,
                const float* __restrict__ W1n, const float* __restrict__ b1n,
                const float* __restrict__ W2n, const float* __restrict__ b2n,
                const float* __restrict__ Wmn, const float* __restrict__ bmn,
                const float* __restrict__ gmn, const float* __restrict__ betamn,
                const float* __restrict__ Wsn, const float* __restrict__ bsn,
                const float* __restrict__ gsn, const float* __restrict__ betasn,
                float* __restrict__ out)
{
  // A: 72-float stride (288B = 18*16B; +16B stagger per slot mod 128B -> bank spread)
  // X: 516-float stride (2064B = 129*16B; 16B stagger per slot)
  __shared__ __align__(16) float Abuf[16 * 72];
  __shared__ __align__(16) float Xbuf[16 * 516];

  const int tid  = threadIdx.x;
  const int lane = tid & 63;
  const int wv   = tid >> 6;
  const int j    = lane >> 4;   // instance-sub within wave
  const int p    = lane & 15;   // column group: cols [4p, 4p+3]
  const int slot = wv * 4 + j;  // 0..15 within block
  const int inst = blockIdx.x * 16 + slot;   // 0..65535  == b*32 + c
  const int c    = inst & 31;
  const bool isp = (c == 0);

  const float4* W1f  = (const float4*)(isp ? W1p : W1n);
  const float4* B1f  = (const float4*)(isp ? b1p : b1n);
  const float4* W2f  = (const float4*)(isp ? W2p : W2n);
  const float4* B2f  = (const float4*)(isp ? b2p : b2n);
  const float4* WMf  = (const float4*)(isp ? Wmp : Wmn);
  const float4* BMf  = (const float4*)(isp ? bmp : bmn);
  const float4* GMf  = (const float4*)(isp ? gmp : gmn);
  const float4* BEMf = (const float4*)(isp ? betamp : betamn);
  const float4* WSf  = (const float4*)(isp ? Wsp : Wsn);
  const float4* BSf  = (const float4*)(isp ? bsp : bsn);
  const float4* GSf  = (const float4*)(isp ? gsp : gsn);
  const float4* BESf = (const float4*)(isp ? betasp : betasn);
  const float4* NZf  = (const float4*)noise;

  // ---- stage raw A: one float4 per lane covers the whole 8x8 ----
  {
    float4 a = ((const float4*)adj)[inst * 16 + p];
    *(float4*)&Abuf[slot * 72 + p * 4] = a;
  }
  __builtin_amdgcn_wave_barrier();

  // ---- row-normalize in place: lanes p<8 each own one row ----
  if (p < 8) {
    float4 r0 = *(const float4*)&Abuf[slot * 72 + p * 8];
    float4 r1 = *(const float4*)&Abuf[slot * 72 + p * 8 + 4];
    float s = r0.x + r0.y + r0.z + r0.w + r1.x + r1.y + r1.z + r1.w;
    s = (s == 0.0f) ? 1.0f : s;
    float rinv = 1.0f / s;
    r0.x *= rinv; r0.y *= rinv; r0.z *= rinv; r0.w *= rinv;
    r1.x *= rinv; r1.y *= rinv; r1.z *= rinv; r1.w *= rinv;
    *(float4*)&Abuf[slot * 72 + p * 8]     = r0;
    *(float4*)&Abuf[slot * 72 + p * 8 + 4] = r1;
  }
  __builtin_amdgcn_wave_barrier();

  // ---- x1 = leaky(A @ W1 + b1) -> Xbuf ----
  {
    float4 w1r[8];
#pragma unroll
    for (int k = 0; k < 8; ++k) w1r[k] = W1f[k * 16 + p];
    const float4 b14 = B1f[p];
#pragma unroll
    for (int i = 0; i < 8; ++i) {
      float4 a0 = *(const float4*)&Abuf[slot * 72 + i * 8];
      float4 a1 = *(const float4*)&Abuf[slot * 72 + i * 8 + 4];
      float4 acc = b14;
      fma4(acc, a0.x, w1r[0]); fma4(acc, a0.y, w1r[1]);
      fma4(acc, a0.z, w1r[2]); fma4(acc, a0.w, w1r[3]);
      fma4(acc, a1.x, w1r[4]); fma4(acc, a1.y, w1r[5]);
      fma4(acc, a1.z, w1r[6]); fma4(acc, a1.w, w1r[7]);
      acc = leaky4(acc);
      *(float4*)&Xbuf[slot * 516 + i * 64 + p * 4] = acc;
    }
  }
  __builtin_amdgcn_wave_barrier();

  // ---- t = x1 @ W2 : stays in registers (x2 contracts over rows of t) ----
  float4 t[8];
#pragma unroll
  for (int i = 0; i < 8; ++i) t[i] = make_float4(0.f, 0.f, 0.f, 0.f);
  {
    const float4* X4 = (const float4*)Xbuf;
    const int xb = slot * 129;
#pragma unroll 2
    for (int kb = 0; kb < 16; ++kb) {
      float4 w0 = W2f[(kb * 4 + 0) * 16 + p];
      float4 w1 = W2f[(kb * 4 + 1) * 16 + p];
      float4 w2 = W2f[(kb * 4 + 2) * 16 + p];
      float4 w3 = W2f[(kb * 4 + 3) * 16 + p];
#pragma unroll
      for (int i = 0; i < 8; ++i) {
        float4 xv = X4[xb + i * 16 + kb];
        fma4(t[i], xv.x, w0); fma4(t[i], xv.y, w1);
        fma4(t[i], xv.z, w2); fma4(t[i], xv.w, w3);
      }
    }
  }
  __builtin_amdgcn_wave_barrier();

  // ---- x2 = leaky(A @ t + b2) -> Xbuf (overwrites x1; same-wave order safe) ----
  {
    const float4 b24 = B2f[p];
#pragma unroll
    for (int i = 0; i < 8; ++i) {
      float4 a0 = *(const float4*)&Abuf[slot * 72 + i * 8];
      float4 a1 = *(const float4*)&Abuf[slot * 72 + i * 8 + 4];
      float4 acc = b24;
      fma4(acc, a0.x, t[0]); fma4(acc, a0.y, t[1]);
      fma4(acc, a0.z, t[2]); fma4(acc, a0.w, t[3]);
      fma4(acc, a1.x, t[4]); fma4(acc, a1.y, t[5]);
      fma4(acc, a1.z, t[6]); fma4(acc, a1.w, t[7]);
      acc = leaky4(acc);
      *(float4*)&Xbuf[slot * 516 + i * 64 + p * 4] = acc;
    }
  }
  __builtin_amdgcn_wave_barrier();

  // ---- m = x2@Wm + bm ; s = x2@Ws + bs (shared x2 reads) ----
  float4 ma[8], sa[8];
#pragma unroll
  for (int i = 0; i < 8; ++i) {
    ma[i] = make_float4(0.f, 0.f, 0.f, 0.f);
    sa[i] = make_float4(0.f, 0.f, 0.f, 0.f);
  }
  {
    const float4* X4 = (const float4*)Xbuf;
    const int xb = slot * 129;
#pragma unroll 1
    for (int kb = 0; kb < 16; ++kb) {
      float4 wm0 = WMf[(kb * 4 + 0) * 16 + p];
      float4 wm1 = WMf[(kb * 4 + 1) * 16 + p];
      float4 wm2 = WMf[(kb * 4 + 2) * 16 + p];
      float4 wm3 = WMf[(kb * 4 + 3) * 16 + p];
      float4 ws0 = WSf[(kb * 4 + 0) * 16 + p];
      float4 ws1 = WSf[(kb * 4 + 1) * 16 + p];
      float4 ws2 = WSf[(kb * 4 + 2) * 16 + p];
      float4 ws3 = WSf[(kb * 4 + 3) * 16 + p];
#pragma unroll
      for (int i = 0; i < 8; ++i) {
        float4 xv = X4[xb + i * 16 + kb];
        fma4(ma[i], xv.x, wm0); fma4(ma[i], xv.y, wm1);
        fma4(ma[i], xv.z, wm2); fma4(ma[i], xv.w, wm3);
        fma4(sa[i], xv.x, ws0); fma4(sa[i], xv.y, ws1);
        fma4(sa[i], xv.z, ws2); fma4(sa[i], xv.w, ws3);
      }
    }
  }

  // ---- biases, BatchNorm over node axis (lane-local!), reparameterize ----
  {
    const float4 bm4 = BMf[p], bs4 = BSf[p];
#pragma unroll
    for (int i = 0; i < 8; ++i) {
      ma[i].x += bm4.x; ma[i].y += bm4.y; ma[i].z += bm4.z; ma[i].w += bm4.w;
      sa[i].x += bs4.x; sa[i].y += bs4.y; sa[i].z += bs4.z; sa[i].w += bs4.w;
    }
    float4 mum = make_float4(0.f, 0.f, 0.f, 0.f);
    float4 mus = make_float4(0.f, 0.f, 0.f, 0.f);
#pragma unroll
    for (int i = 0; i < 8; ++i) {
      mum.x += ma[i].x; mum.y += ma[i].y; mum.z += ma[i].z; mum.w += ma[i].w;
      mus.x += sa[i].x; mus.y += sa[i].y; mus.z += sa[i].z; mus.w += sa[i].w;
    }
    mum.x *= 0.125f; mum.y *= 0.125f; mum.z *= 0.125f; mum.w *= 0.125f;
    mus.x *= 0.125f; mus.y *= 0.125f; mus.z *= 0.125f; mus.w *= 0.125f;
    float4 vam = make_float4(0.f, 0.f, 0.f, 0.f);
    float4 vas = make_float4(0.f, 0.f, 0.f, 0.f);
#pragma unroll
    for (int i = 0; i < 8; ++i) {
      float dx, dy, dz, dw;
      dx = ma[i].x - mum.x; dy = ma[i].y - mum.y; dz = ma[i].z - mum.z; dw = ma[i].w - mum.w;
      vam.x = fmaf(dx, dx, vam.x); vam.y = fmaf(dy, dy, vam.y);
      vam.z = fmaf(dz, dz, vam.z); vam.w = fmaf(dw, dw, vam.w);
      dx = sa[i].x - mus.x; dy = sa[i].y - mus.y; dz = sa[i].z - mus.z; dw = sa[i].w - mus.w;
      vas.x = fmaf(dx, dx, vas.x); vas.y = fmaf(dy, dy, vas.y);
      vas.z = fmaf(dz, dz, vas.z); vas.w = fmaf(dw, dw, vas.w);
    }
    vam.x *= 0.125f; vam.y *= 0.125f; vam.z *= 0.125f; vam.w *= 0.125f;
    vas.x *= 0.125f; vas.y *= 0.125f; vas.z *= 0.125f; vas.w *= 0.125f;

    const float4 gm4 = GMf[p], bem4 = BEMf[p];
    const float4 gs4 = GSf[p], bes4 = BESf[p];
    float4 sclm, scls;
    sclm.x = gm4.x / sqrtf(vam.x + BN_EPS); sclm.y = gm4.y / sqrtf(vam.y + BN_EPS);
    sclm.z = gm4.z / sqrtf(vam.z + BN_EPS); sclm.w = gm4.w / sqrtf(vam.w + BN_EPS);
    scls.x = gs4.x / sqrtf(vas.x + BN_EPS); scls.y = gs4.y / sqrtf(vas.y + BN_EPS);
    scls.z = gs4.z / sqrtf(vas.z + BN_EPS); scls.w = gs4.w / sqrtf(vas.w + BN_EPS);

    const float K = 0.7213475204444817f;  // 0.5 * log2(e): exp(0.5x)=exp2(K*x)
    float4* out4 = (float4*)out;
#pragma unroll
    for (int i = 0; i < 8; ++i) {
      float4 n4 = NZf[i * 16 + p];
      float4 o;
      float lvx = (sa[i].x - mus.x) * scls.x + bes4.x;
      float lvy = (sa[i].y - mus.y) * scls.y + bes4.y;
      float lvz = (sa[i].z - mus.z) * scls.z + bes4.z;
      float lvw = (sa[i].w - mus.w) * scls.w + bes4.w;
      o.x = (ma[i].x - mum.x) * sclm.x + bem4.x + exp2f(K * lvx) * n4.x;
      o.y = (ma[i].y - mum.y) * sclm.y + bem4.y + exp2f(K * lvy) * n4.y;
      o.z = (ma[i].z - mum.z) * sclm.z + bem4.z + exp2f(K * lvz) * n4.z;
      o.w = (ma[i].w - mum.w) * sclm.w + bem4.w + exp2f(K * lvw) * n4.w;
      out4[inst * 128 + i * 16 + p] = o;
    }
  }
}

extern "C" void kernel_launch(void* const* d_in, const int* in_sizes, int n_in,
                              void* d_out, int out_size, void* d_ws, size_t ws_size,
                              hipStream_t stream) {
  const float* adj   = (const float*)d_in[0];
  const float* noise = (const float*)d_in[1];
  const float* W1p = (const float*)d_in[2];  const float* b1p = (const float*)d_in[3];
  const float* W2p = (const float*)d_in[4];  const float* b2p = (const float*)d_in[5];
  const float* Wmp = (const float*)d_in[6];  const float* bmp = (const float*)d_in[7];
  const float* gmp = (const float*)d_in[8];  const float* betamp = (const float*)d_in[9];
  const float* Wsp = (const float*)d_in[10]; const float* bsp = (const float*)d_in[11];
  const float* gsp = (const float*)d_in[12]; const float* betasp = (const float*)d_in[13];
  const float* W1n = (const float*)d_in[14]; const float* b1n = (const float*)d_in[15];
  const float* W2n = (const float*)d_in[16]; const float* b2n = (const float*)d_in[17];
  const float* Wmn = (const float*)d_in[18]; const float* bmn = (const float*)d_in[19];
  const float* gmn = (const float*)d_in[20]; const float* betamn = (const float*)d_in[21];
  const float* Wsn = (const float*)d_in[22]; const float* bsn = (const float*)d_in[23];
  const float* gsn = (const float*)d_in[24]; const float* betasn = (const float*)d_in[25];

  enc_kernel<<<4096, 256, 0, stream>>>(
      adj, noise,
      W1p, b1p, W2p, b2p, Wmp, bmp, gmp, betamp, Wsp, bsp, gsp, betasp,
      W1n, b1n, W2n, b2n, Wmn, bmn, gmn, betamn, Wsn, bsn, gsn, betasn,
      (float*)d_out);
}